// Round 14
// baseline (206.793 us; speedup 1.0000x reference)
//
#include <hip/hip_runtime.h>
#include <hip/hip_bf16.h>

// TAttention: B=16, C=32, N=1024, T=128, R=10
//  K1 k_reduce_c : k[b,n,t] = sum_c alpha[c]*x[b,c,n,t]    (256 MB read, BW)
//  K2 kw_partial2: p_w[b][r][ch32][t] partials             (8 MB, fast)
//  K3 scores_softmax3: partial-reduce + scores + softmax -> att bf16 (tiny)
//  K4 out_gemm9  : persistent block = (b,c), 16 slabs, DEPTH-2 reg prefetch.
//     Theory: depth-1 prefetch drains vmcnt at each iter's ds_write ->
//     loads outstanding only ~45% of the time -> 15 GB/s/CU. Depth-2 keeps
//     8KB/wave outstanding across the whole iteration (compiler emits
//     vmcnt(8): waits old batch only). att staged once per 16 slabs.
// Dead theories (measured): barrier drain(R7), store scatter(R11), occupancy
// (R10), LDS conflicts(0), L2 thrash/nt(R13), direct-reg frags(R5/R8/R10),
// bf16 echo(R3/R9), per-block softmax(R4).

#define B_ 16
#define C_ 32
#define N_ 1024
#define T_ 128
#define R_ 10

typedef __bf16 bf16x8 __attribute__((ext_vector_type(8)));
typedef __bf16 bf16x4 __attribute__((ext_vector_type(4)));
typedef float f32x4 __attribute__((ext_vector_type(4)));

__device__ __forceinline__ void lds_barrier() {
    asm volatile("s_waitcnt lgkmcnt(0)" ::: "memory");
    __builtin_amdgcn_s_barrier();
    asm volatile("" ::: "memory");
}

// ---------------------------------------------------------------- kernel 1
__global__ __launch_bounds__(256) void k_reduce_c(const float* __restrict__ x,
                                                  const float* __restrict__ alpha,
                                                  float* __restrict__ k) {
    int bid = blockIdx.x;            // B * N/8 = 2048
    int b   = bid >> 7;
    int nc  = bid & 127;
    int tid = threadIdx.x;
    int nl  = tid >> 5;
    int lc  = tid & 31;
    int n   = nc * 8 + nl;
    const float4* xb = reinterpret_cast<const float4*>(
        x + ((size_t)(b * C_) * N_ + n) * T_) + lc;
    float4 acc = {0.f, 0.f, 0.f, 0.f};
    #pragma unroll 8
    for (int c = 0; c < C_; ++c) {
        float a = alpha[c];
        float4 v = xb[(size_t)c * (N_ * T_ / 4)];
        acc.x += a * v.x; acc.y += a * v.y; acc.z += a * v.z; acc.w += a * v.w;
    }
    reinterpret_cast<float4*>(k + ((size_t)b * N_ + n) * T_)[lc] = acc;
}

// ---------------------------------------------------------------- kernel 2
__global__ __launch_bounds__(128) void kw_partial2(const float* __restrict__ k,
                                                   const float* __restrict__ W1,
                                                   const float* __restrict__ W2,
                                                   float* __restrict__ p1,
                                                   float* __restrict__ p2) {
    __shared__ float wl[32][20];
    int bid = blockIdx.x;            // b*32 + ch
    int b   = bid >> 5;
    int ch  = bid & 31;
    int n0  = ch * 32;
    int t   = threadIdx.x;
    for (int i = t; i < 32 * 20; i += 128) {
        int nl = i & 31, q = i >> 5;
        wl[nl][q] = (q < 10) ? W1[q * N_ + n0 + nl] : W2[(q - 10) * N_ + n0 + nl];
    }
    __syncthreads();
    float a1[R_] = {}, a2[R_] = {};
    const float* kb = k + ((size_t)b * N_ + n0) * T_ + t;
    #pragma unroll 2
    for (int g = 0; g < 4; ++g) {
        float kv[8];
        #pragma unroll
        for (int j = 0; j < 8; ++j) kv[j] = kb[(g * 8 + j) * T_];
        #pragma unroll
        for (int j = 0; j < 8; ++j) {
            int nl = g * 8 + j;
            #pragma unroll
            for (int r = 0; r < R_; ++r) {
                a1[r] += kv[j] * wl[nl][r];
                a2[r] += kv[j] * wl[nl][10 + r];
            }
        }
    }
    #pragma unroll
    for (int r = 0; r < R_; ++r) {
        size_t o = (((size_t)b * R_ + r) * 32 + ch) * T_ + t;
        p1[o] = a1[r];
        p2[o] = a2[r];
    }
}

// ---------------------------------------------------------------- kernel 3
__global__ __launch_bounds__(128) void scores_softmax3(const float* __restrict__ p1,
                                                       const float* __restrict__ p2,
                                                       __bf16* __restrict__ att) {
    __shared__ __align__(16) float kw1s[T_][12];
    __shared__ __align__(16) float kw2s[T_][12];
    __shared__ float sc[T_][T_ + 1];
    int b = blockIdx.x;
    int t = threadIdx.x;
    #pragma unroll
    for (int r = 0; r < R_; ++r) {
        float s1 = 0.f, s2 = 0.f;
        const float* q1 = p1 + (((size_t)b * R_ + r) * 32) * T_ + t;
        const float* q2 = p2 + (((size_t)b * R_ + r) * 32) * T_ + t;
        #pragma unroll 4
        for (int ch = 0; ch < 32; ++ch) { s1 += q1[ch * T_]; s2 += q2[ch * T_]; }
        kw1s[t][r] = s1; kw2s[t][r] = s2;
    }
    __syncthreads();
    float myw[R_];
    #pragma unroll
    for (int r = 0; r < R_; ++r) myw[r] = kw1s[t][r];
    float mx = -1e30f;
    for (int s = 0; s < T_; ++s) {
        float wv[12];
        const float4* qr = reinterpret_cast<const float4*>(&kw2s[s][0]);
        #pragma unroll
        for (int q = 0; q < 3; ++q) *reinterpret_cast<float4*>(&wv[q * 4]) = qr[q];
        float v = 0.f;
        #pragma unroll
        for (int r = 0; r < R_; ++r) v += myw[r] * wv[r];
        sc[t][s] = v;
        mx = fmaxf(mx, v);
    }
    float sum = 0.f;
    for (int s = 0; s < T_; ++s) {
        float e = __expf(sc[t][s] - mx);
        sc[t][s] = e;
        sum += e;
    }
    float inv = 1.0f / sum;
    __bf16* arow = att + ((size_t)b * T_ + t) * T_;
    for (int s8 = 0; s8 < T_; s8 += 8) {
        bf16x8 hv;
        #pragma unroll
        for (int q = 0; q < 8; ++q) hv[q] = (__bf16)(sc[t][s8 + q] * inv);
        *reinterpret_cast<bf16x8*>(arow + s8) = hv;
    }
}

// ---------------------------------------------------------------- kernel 4
// persistent block = (b,c): 16 slabs of 64 n-rows. Depth-2 register
// prefetch: at iter i, issue slab i+2 into set (i&1); ds_write slab i+1
// (set (i+1)&1) at iter end. Compiler waits only the older 8 loads
// (vmcnt(8)) -> the newer 8 stay in flight across the barrier.
__global__ __launch_bounds__(256, 2) void out_gemm9(const float* __restrict__ x,
                                                    const __bf16* __restrict__ att,
                                                    float* __restrict__ out) {
    __shared__ __align__(16) __bf16 attl[T_][T_];      // 32 KB swizzled
    __shared__ __align__(16) __bf16 xsl[2][64][T_];    // 2 x 16 KB swizzled
    int bid = blockIdx.x;            // b*32 + c   (512 blocks = 2/CU resident)
    int c   = bid & 31;
    int b   = bid >> 5;
    int tid = threadIdx.x;
    char* attb = (char*)&attl[0][0];
    size_t base = ((size_t)(b * C_ + c) * N_) * T_;

    // ---- prologue: att + slab0 + slab1 loads; stage att, ds_write slab0
    const uint4* ga = reinterpret_cast<const uint4*>(att + (size_t)b * T_ * T_);
    uint4 ar[8];
    #pragma unroll
    for (int i = 0; i < 8; ++i) ar[i] = ga[i * 256 + tid];
    f32x4 xs[2][8];
    {
        const f32x4* g0 = reinterpret_cast<const f32x4*>(x + base);
        #pragma unroll
        for (int j = 0; j < 8; ++j) xs[0][j] = g0[j * 256 + tid];
        const f32x4* g1 = reinterpret_cast<const f32x4*>(x + base + (size_t)64 * T_);
        #pragma unroll
        for (int j = 0; j < 8; ++j) xs[1][j] = g1[j * 256 + tid];
    }
    #pragma unroll
    for (int i = 0; i < 8; ++i) {
        int e = i * 256 + tid, row = e >> 4;
        int bc = ((e & 15) * 16) ^ ((row & 7) << 4);
        *reinterpret_cast<uint4*>(attb + row * 256 + bc) = ar[i];
    }
    {   // ds_write slab0 -> buf0
        char* xw = (char*)&xsl[0][0][0];
        #pragma unroll
        for (int j = 0; j < 8; ++j) {
            int e = j * 256 + tid, row = e >> 5;
            bf16x4 hv = {(__bf16)xs[0][j][0], (__bf16)xs[0][j][1],
                         (__bf16)xs[0][j][2], (__bf16)xs[0][j][3]};
            *reinterpret_cast<bf16x4*>(xw + row * 256 + (((e & 31) * 8) ^ ((row & 7) << 4))) = hv;
        }
    }
    lds_barrier();

    int wave = tid >> 6, lane = tid & 63;
    int r16 = lane & 15, g = lane >> 4;
    int wt = wave & 1, wn = wave >> 1;
    int swz = (r16 & 7) << 4;

    #pragma unroll
    for (int i = 0; i < 16; ++i) {
        // depth-2 issue: slab i+2 into the set freed at iter i-1 (or prologue)
        if (i < 14) {
            const f32x4* gn = reinterpret_cast<const f32x4*>(
                x + base + ((size_t)(i + 2) * 64) * T_);
            #pragma unroll
            for (int j = 0; j < 8; ++j) xs[i & 1][j] = gn[j * 256 + tid];
        }
        // MFMA on slab i from buf[i&1] (verified R2 core)
        const char* xbb = (const char*)&xsl[i & 1][0][0];
        f32x4 acc[2][4] = {};
        #pragma unroll
        for (int ks = 0; ks < 4; ++ks) {
            int kc = ks * 64 + g * 16;
            bf16x8 a[4], bx[2];
            #pragma unroll
            for (int tt = 0; tt < 4; ++tt)
                a[tt] = *reinterpret_cast<const bf16x8*>(
                    attb + (wt * 64 + tt * 16 + r16) * 256 + (kc ^ swz));
            #pragma unroll
            for (int nn = 0; nn < 2; ++nn)
                bx[nn] = *reinterpret_cast<const bf16x8*>(
                    xbb + (wn * 32 + nn * 16 + r16) * 256 + (kc ^ swz));
            #pragma unroll
            for (int nn = 0; nn < 2; ++nn)
                #pragma unroll
                for (int tt = 0; tt < 4; ++tt)
                    acc[nn][tt] = __builtin_amdgcn_mfma_f32_16x16x32_bf16(
                        a[tt], bx[nn], acc[nn][tt], 0, 0, 0);
        }
        // stores (never waited on)
        float* o = out + base + ((size_t)i * 64) * T_;
        #pragma unroll
        for (int nn = 0; nn < 2; ++nn) {
            int n_l = wn * 32 + nn * 16 + r16;
            #pragma unroll
            for (int tt = 0; tt < 4; ++tt)
                *reinterpret_cast<f32x4*>(
                    o + (size_t)n_l * T_ + (wt * 64 + tt * 16 + g * 4)) = acc[nn][tt];
        }
        // ds_write slab i+1 (older reg set) -> buf[(i+1)&1]; one barrier/iter
        if (i < 15) {
            char* xw = (char*)&xsl[(i + 1) & 1][0][0];
            #pragma unroll
            for (int j = 0; j < 8; ++j) {
                int e = j * 256 + tid, row = e >> 5;
                bf16x4 hv = {(__bf16)xs[(i + 1) & 1][j][0], (__bf16)xs[(i + 1) & 1][j][1],
                             (__bf16)xs[(i + 1) & 1][j][2], (__bf16)xs[(i + 1) & 1][j][3]};
                *reinterpret_cast<bf16x4*>(
                    xw + row * 256 + (((e & 31) * 8) ^ ((row & 7) << 4))) = hv;
            }
            lds_barrier();
        }
    }
}

// ----------------------------------------------------------------
extern "C" void kernel_launch(void* const* d_in, const int* in_sizes, int n_in,
                              void* d_out, int out_size, void* d_ws, size_t ws_size,
                              hipStream_t stream) {
    const float* x     = (const float*)d_in[0];
    const float* W1    = (const float*)d_in[1];
    const float* W2    = (const float*)d_in[2];
    const float* alpha = (const float*)d_in[3];
    float* out = (float*)d_out;

    const size_t KSZ = (size_t)B_ * N_ * T_;            // f32
    const size_t PSZ = (size_t)B_ * R_ * 32 * T_;       // f32
    float* k    = (float*)d_ws;
    float* p1   = k + KSZ;
    float* p2   = p1 + PSZ;
    __bf16* att = (__bf16*)(p2 + PSZ);                  // [b][t][s]

    k_reduce_c     <<<dim3(B_ * (N_ / 8)), dim3(256), 0, stream>>>(x, alpha, k);
    kw_partial2    <<<dim3(B_ * 32),       dim3(128), 0, stream>>>(k, W1, W2, p1, p2);
    scores_softmax3<<<dim3(B_),            dim3(128), 0, stream>>>(p1, p2, att);
    out_gemm9      <<<dim3(B_ * C_),       dim3(256), 0, stream>>>(x, att, out);
}